// Round 15
// baseline (217.168 us; speedup 1.0000x reference)
//
#include <hip/hip_runtime.h>

#define NB 4
#define SS 2048
#define DMODEL 1024
#define DHEAD 64
// SCALE = sqrt(1024) = 32 exactly; folded into Wt3 for mode 0 (and bias at use).
// Softmax WITHOUT max subtraction: s ~ N(0,0.25), exp safe in f32.
// Softmax over the QUERY axis (reference quirk): r[k] = 1/sum_q exp(s[q,k]).
// R15: TWO dispatches. mega = k1 -> gridbar -> k2 x2 -> gridbar -> kab with
// hand-rolled device-atomic grid barriers (normal launch, graph-capturable).
// Co-residency guaranteed: 512 blocks x 256 thr x LDS<=32KB (>=2 blocks/CU
// under any accounting). threadfence release/acquire spans XCD L2s (G16).
// Counters re-zeroed every replay by k0init. clock64 bailout prevents hangs.

typedef __bf16 bf16x8 __attribute__((ext_vector_type(8)));
typedef __bf16 bf16x4 __attribute__((ext_vector_type(4)));
typedef float f32x4 __attribute__((ext_vector_type(4)));

#define MFMA16(a, b, c) __builtin_amdgcn_mfma_f32_16x16x32_bf16((a), (b), (c), 0, 0, 0)

// Kb3 frag addr (elems): ((b*256 + t*2 + h) << 9) + ln*8 + i   (t=k>>4, h=d>>5)
// Vt3 frag addr (elems): ((b*256 + kc*4 + nt) << 9) + ln*8 + i (kc=k>>5, nt=d>>4)

// ---------------- grid barrier (single-use per launch, counters pre-zeroed) --
__device__ __forceinline__ void grid_barrier(int* cnt, int nb)
{
    __threadfence();                          // release: L2 writeback (agent scope)
    __syncthreads();
    if (threadIdx.x == 0) {
        atomicAdd(cnt, 1);
        long long t0 = clock64();
        while (atomicAdd(cnt, 0) < nb) {
            __builtin_amdgcn_s_sleep(8);
            if (clock64() - t0 > 200000000LL) break;   // ~83ms bailout: fail, not hang
        }
    }
    __syncthreads();
    __threadfence();                          // acquire: invalidate stale caches
}

// ---------------- Dispatch 1: Wt3 transpose + zero barrier counters ---------
__global__ __launch_bounds__(256) void k0init(
    const float* __restrict__ Wq, const float* __restrict__ Wk,
    const float* __restrict__ Wv, __bf16* __restrict__ Wt3, int* __restrict__ bar)
{
    if (blockIdx.x == 0 && threadIdx.x < 8) bar[threadIdx.x] = 0;
    int idx = blockIdx.x * 256 + threadIdx.x;  // 0..24575
    int kc = idx / 768;
    int rem = idx - kc * 768;
    int f = rem >> 6;
    int lane = rem & 63;
    int g = lane >> 4, l15 = lane & 15;
    int mode = f >> 2, nt = f & 3;
    const float* W = (mode == 0) ? Wq : (mode == 1 ? Wk : Wv);
    const float s = (mode == 0) ? 0.03125f : 1.0f;
    int n = nt * 16 + l15;
    int k = kc * 32 + g * 8;
    bf16x8 o;
    #pragma unroll
    for (int i = 0; i < 8; ++i)
        o[i] = (__bf16)(W[(size_t)(k + i) * DHEAD + n] * s);
    *(bf16x8*)(Wt3 + (size_t)idx * 8) = o;
}

// ---------------- Phase 1: fused Q/K/V projection (one 16-row tile) ---------
// stage = 16x1024 bf16 = 32KB EXACT, XOR-swizzled (byte ^ ((row&7)<<4)) for
// conflict-free ds_read_b128 (rows r, r+8 alias -> 2-way = free). Reduction in
// two 6-frag rounds (red 18KB). Outstage 6KB @18432. Max LDS use: 32KB.
__device__ __forceinline__ void phase_k1(
    char* smem, const float* __restrict__ x, const __bf16* __restrict__ Wt3,
    const float* __restrict__ bq, const float* __restrict__ bk,
    const float* __restrict__ bv,
    __bf16* __restrict__ Qo, __bf16* __restrict__ Kb3, __bf16* __restrict__ Vt3,
    int bx)
{
    const int tid = threadIdx.x;
    const int wid = tid >> 6;
    const int lane = tid & 63;
    const int l15 = lane & 15;
    const int g = lane >> 4;
    const int row0 = bx * 16;
    const int b  = row0 >> 11;
    const int s0 = row0 & 2047;
    const int soff = (s0 >> 3) & 2;

    {   // stage x[row0..+16][0..1024) f32 -> bf16, coalesced, XOR-swizzled
        const float* xsrc = x + (size_t)row0 * DMODEL;
        #pragma unroll
        for (int it = 0; it < 16; ++it) {
            int row = it;                     // one row per iteration
            int byte = tid * 8;               // 8B chunk per thread
            f32x4 v = *(const f32x4*)(xsrc + (size_t)row * DMODEL + tid * 4);
            bf16x4 b4;
            #pragma unroll
            for (int i = 0; i < 4; ++i) b4[i] = (__bf16)v[i];
            *(bf16x4*)(smem + row * 2048 + (byte ^ ((row & 7) << 4))) = b4;
        }
    }
    __syncthreads();

    f32x4 acc[12];
    #pragma unroll
    for (int f = 0; f < 12; ++f) acc[f] = (f32x4){0.f, 0.f, 0.f, 0.f};

    const int swzrow = (l15 & 7) << 4;
    #pragma unroll
    for (int c = 0; c < 8; ++c) {
        int byte = (wid * 256 + c * 32 + g * 8) * 2;
        bf16x8 af = *(const bf16x8*)(smem + l15 * 2048 + (byte ^ swzrow));
        const int kc = wid * 8 + c;
        #pragma unroll
        for (int f = 0; f < 12; ++f) {
            bf16x8 bfr = *(const bf16x8*)(Wt3 + (((size_t)kc * 12 + f) << 9) + lane * 8);
            acc[f] = MFMA16(af, bfr, acc[f]);
        }
    }

    f32x4* red = (f32x4*)smem;                // [3][6][64] = 18KB (stage dead after sync)
    __bf16* outQ = (__bf16*)(smem + 18432);   // [16][64] 2KB
    __bf16* outK = outQ + 1024;               // 2 frags x 512 elems 2KB
    __bf16* outV = outK + 1024;               // 4 x 256 elems 2KB
    for (int rd = 0; rd < 2; ++rd) {
        __syncthreads();                      // stage/prev-round reads done
        if (wid != 0) {
            #pragma unroll
            for (int f6 = 0; f6 < 6; ++f6)
                red[((wid - 1) * 6 + f6) * 64 + lane] = acc[rd * 6 + f6];
        }
        __syncthreads();
        if (wid == 0) {
            #pragma unroll
            for (int f6 = 0; f6 < 6; ++f6) {
                const int f = rd * 6 + f6;
                f32x4 a = acc[f] + red[(0 * 6 + f6) * 64 + lane]
                        + red[(1 * 6 + f6) * 64 + lane] + red[(2 * 6 + f6) * 64 + lane];
                const int md = f >> 2, nt = f & 3;
                const int n = nt * 16 + l15;
                const float* bias = (md == 0) ? bq : (md == 1 ? bk : bv);
                const float bscale = (md == 0) ? 0.03125f : 1.0f;
                float bvl = bias[n] * bscale;
                #pragma unroll
                for (int r = 0; r < 4; ++r) {
                    float o = a[r] + bvl;
                    int g4r = g * 4 + r;
                    if (md == 0) {
                        outQ[g4r * 64 + n] = (__bf16)o;
                    } else if (md == 1) {
                        int ln = ((nt & 1) * 2 + (l15 >> 3)) * 16 + g4r;
                        outK[(nt >> 1) * 512 + ln * 8 + (l15 & 7)] = (__bf16)o;
                    } else {
                        outV[nt * 256 + ((g4r >> 3) * 16 + l15) * 8 + (g4r & 7)] = (__bf16)o;
                    }
                }
            }
        }
    }
    __syncthreads();
    // cooperative coalesced stores
    if (tid < 128) {
        *(bf16x8*)(Qo + ((size_t)b * SS + s0) * DHEAD + tid * 8) = *(bf16x8*)(outQ + tid * 8);
        int nt = tid >> 5, e = (tid & 31) * 8;
        *(bf16x8*)(Vt3 + (((size_t)(b * 256 + (s0 >> 5) * 4 + nt)) << 9) + soff * 128 + e)
            = *(bf16x8*)(outV + nt * 256 + e);
    } else {
        int t2 = tid - 128;
        *(bf16x8*)(Kb3 + (((size_t)b * 256 + (s0 >> 4) * 2) << 9) + t2 * 8) = *(bf16x8*)(outK + t2 * 8);
    }
}

// ---------------- Phase 2: column exp-sum partials (one unit) ----------------
#define QST 72
__device__ __forceinline__ void phase_k2(
    char* smem, const __bf16* __restrict__ Qb, const __bf16* __restrict__ Kb3,
    float* __restrict__ partial, int bx)
{
    __bf16* qt = (__bf16*)smem;               // [128][72] 18.4 KB
    const int tid = threadIdx.x;
    const int wid = tid >> 6;
    const int lane = tid & 63;
    const int l15 = lane & 15;
    const int g = lane >> 4;
    const int b  = bx >> 8;
    const int rem = bx & 255;
    const int kg = rem >> 4;
    const int qs = rem & 15;
    const int k0 = kg * 128 + wid * 32;

    __syncthreads();                          // protect qt reuse
    {   // stage Q rows [qs*128,+128): 16 KB contiguous
        const __bf16* qsrc = Qb + ((size_t)(b * SS + qs * 128)) * DHEAD;
        #pragma unroll
        for (int it = 0; it < 4; ++it) {
            int idx = it * 256 + tid;
            int row = idx >> 3;
            int col = (idx & 7) * 8;
            *(bf16x8*)(qt + row * QST + col) = *(const bf16x8*)(qsrc + (size_t)idx * 8);
        }
    }

    const __bf16* kfr = Kb3 + (((size_t)b * 256 + (k0 >> 4) * 2) << 9) + lane * 8;
    bf16x8 ka00 = *(const bf16x8*)(kfr);
    bf16x8 ka01 = *(const bf16x8*)(kfr + 512);
    bf16x8 ka10 = *(const bf16x8*)(kfr + 1024);
    bf16x8 ka11 = *(const bf16x8*)(kfr + 1536);
    __syncthreads();

    f32x4 cs0 = (f32x4){0.f, 0.f, 0.f, 0.f};
    f32x4 cs1 = (f32x4){0.f, 0.f, 0.f, 0.f};

    #pragma unroll 2
    for (int j = 0; j < 8; ++j) {
        const __bf16* qr = qt + (j * 16 + l15) * QST + g * 8;
        bf16x8 qb0 = *(const bf16x8*)(qr);
        bf16x8 qb1 = *(const bf16x8*)(qr + 32);
        f32x4 s0 = (f32x4){0.f, 0.f, 0.f, 0.f};
        s0 = MFMA16(ka00, qb0, s0);
        s0 = MFMA16(ka01, qb1, s0);
        f32x4 s1 = (f32x4){0.f, 0.f, 0.f, 0.f};
        s1 = MFMA16(ka10, qb0, s1);
        s1 = MFMA16(ka11, qb1, s1);
        #pragma unroll
        for (int r = 0; r < 4; ++r) {
            cs0[r] += __expf(s0[r]);
            cs1[r] += __expf(s1[r]);
        }
    }
    #pragma unroll
    for (int off = 1; off < 16; off <<= 1) {
        #pragma unroll
        for (int r = 0; r < 4; ++r) {
            cs0[r] += __shfl_xor(cs0[r], off);
            cs1[r] += __shfl_xor(cs1[r], off);
        }
    }
    if (l15 == 0) {
        float* pp = partial + (size_t)qs * (NB * SS) + b * SS + k0 + 4 * g;
        *(f32x4*)(pp)      = cs0;
        *(f32x4*)(pp + 16) = cs1;
    }
}

// ---------------- Phase 3: out = (exp(S).*r + mask) @ V  (one q-tile) -------
// 4 waves; wave wid owns [wid*512,+512) = 16 steps of 32. rl prologue folds
// k2b; e-transpose via shuffle (R11-proven); mask loaded DIRECTLY in A-frag
// pattern (R14-proven). LDS: rl 8KB | red 16KB @8192 -> max 24KB.
__device__ __forceinline__ void phase_kab(
    char* smem, const __bf16* __restrict__ Qb, const __bf16* __restrict__ Kb3,
    const __bf16* __restrict__ Vt3, const float* __restrict__ mask,
    const float* __restrict__ part, float* __restrict__ out, int bx)
{
    float* rl = (float*)smem;                 // 8 KB
    f32x4* red = (f32x4*)(smem + 8192);       // [4][4][64] 16 KB
    const int tid = threadIdx.x;
    const int wid = tid >> 6;
    const int lane = tid & 63;
    const int l15 = lane & 15;
    const int g = lane >> 4;
    const int b  = bx >> 7;
    const int q0 = (bx & 127) * 16;

    __syncthreads();                          // protect smem reuse from k2
    {   // r prologue: 8 k per thread (256 thr x 8 = 2048)
        const int k = tid * 8;
        f32x4 sa = (f32x4){0.f, 0.f, 0.f, 0.f};
        f32x4 sb = (f32x4){0.f, 0.f, 0.f, 0.f};
        #pragma unroll
        for (int qs = 0; qs < 16; ++qs) {
            const float* pp = part + (size_t)qs * (NB * SS) + b * SS + k;
            sa += *(const f32x4*)(pp);
            sb += *(const f32x4*)(pp + 4);
        }
        f32x4 ra, rb;
        #pragma unroll
        for (int r = 0; r < 4; ++r) { ra[r] = 1.0f / sa[r]; rb[r] = 1.0f / sb[r]; }
        *(f32x4*)(rl + k) = ra;
        *(f32x4*)(rl + k + 4) = rb;
    }

    const __bf16* qp = Qb + ((size_t)(b * SS + q0 + l15)) * DHEAD + g * 8;
    bf16x8 qb0 = *(const bf16x8*)(qp);
    bf16x8 qb1 = *(const bf16x8*)(qp + 32);
    __syncthreads();                          // rl ready

    f32x4 acc[4];
    #pragma unroll
    for (int nt = 0; nt < 4; ++nt) acc[nt] = (f32x4){0.f, 0.f, 0.f, 0.f};
    const float* mrowA = mask + ((size_t)(b * SS + q0 + l15)) * SS + g * 8;

    #pragma unroll 2
    for (int st = 0; st < 16; ++st) {
        const int kbase = wid * 512 + st * 32;
        const __bf16* kfr = Kb3 + (((size_t)b * 256 + (kbase >> 4) * 2) << 9) + lane * 8;
        bf16x8 ka00 = *(const bf16x8*)(kfr);
        bf16x8 ka01 = *(const bf16x8*)(kfr + 512);
        bf16x8 ka10 = *(const bf16x8*)(kfr + 1024);
        bf16x8 ka11 = *(const bf16x8*)(kfr + 1536);
        const __bf16* vfr = Vt3 + (((size_t)b * 256 + (kbase >> 5) * 4) << 9) + lane * 8;
        bf16x8 vb0 = *(const bf16x8*)(vfr);
        bf16x8 vb1 = *(const bf16x8*)(vfr + 512);
        bf16x8 vb2 = *(const bf16x8*)(vfr + 1024);
        bf16x8 vb3 = *(const bf16x8*)(vfr + 1536);
        f32x4 mk0 = *(const f32x4*)(mrowA + kbase);
        f32x4 mk1 = *(const f32x4*)(mrowA + kbase + 4);

        f32x4 s0 = (f32x4){0.f, 0.f, 0.f, 0.f};
        s0 = MFMA16(ka00, qb0, s0);
        s0 = MFMA16(ka01, qb1, s0);
        f32x4 s1 = (f32x4){0.f, 0.f, 0.f, 0.f};
        s1 = MFMA16(ka10, qb0, s1);
        s1 = MFMA16(ka11, qb1, s1);

        f32x4 rv0 = *(const f32x4*)(rl + kbase + 4 * g);
        f32x4 rv1 = *(const f32x4*)(rl + kbase + 16 + 4 * g);
        f32x4 e0, e1;
        #pragma unroll
        for (int r = 0; r < 4; ++r) {
            e0[r] = __expf(s0[r]) * rv0[r];
            e1[r] = __expf(s1[r]) * rv1[r];
        }
        // shuffle transpose (R11-proven): af[i] = P~[q=l15][kbase+8g+i] + mask
        bf16x8 af;
        #pragma unroll
        for (int i = 0; i < 8; ++i) {
            int src = l15 + 16 * ((2 * g + (i >> 2)) & 3);
            float v0 = __shfl(e0[i & 3], src);
            float v1 = __shfl(e1[i & 3], src);
            af[i] = (__bf16)((g < 2 ? v0 : v1) + (i < 4 ? mk0[i & 3] : mk1[i & 3]));
        }
        acc[0] = MFMA16(af, vb0, acc[0]);
        acc[1] = MFMA16(af, vb1, acc[1]);
        acc[2] = MFMA16(af, vb2, acc[2]);
        acc[3] = MFMA16(af, vb3, acc[3]);
    }
    __syncthreads();
    #pragma unroll
    for (int nt = 0; nt < 4; ++nt) red[(wid * 4 + nt) * 64 + lane] = acc[nt];
    __syncthreads();
    float* outO = (float*)smem;               // 4KB alias over rl (rl dead)
    if (wid == 0) {
        #pragma unroll
        for (int nt = 0; nt < 4; ++nt) {
            f32x4 a = red[nt * 64 + lane] + red[(4 + nt) * 64 + lane]
                    + red[(8 + nt) * 64 + lane] + red[(12 + nt) * 64 + lane];
            #pragma unroll
            for (int r = 0; r < 4; ++r)
                outO[(g * 4 + r) * 64 + nt * 16 + l15] = a[r];
        }
    }
    __syncthreads();
    {
        int row = tid >> 4, col = (tid & 15) * 4;
        *(f32x4*)(out + ((size_t)(b * SS + q0 + row)) * DHEAD + col)
            = *(const f32x4*)(outO + row * 64 + col);
    }
}

// ---------------- Dispatch 2: mega (k1 -> gbar -> k2 x2 -> gbar -> kab) -----
__global__ __launch_bounds__(256) void mega(
    const float* __restrict__ x, const float* __restrict__ mask,
    const float* __restrict__ bq, const float* __restrict__ bk,
    const float* __restrict__ bv,
    __bf16* __restrict__ Qbf, __bf16* __restrict__ Kb3, __bf16* __restrict__ Vt3,
    float* __restrict__ part, const __bf16* __restrict__ Wt3,
    int* __restrict__ bar, float* __restrict__ out)
{
    __shared__ char smem[32768];
    const int nb = gridDim.x;

    phase_k1(smem, x, Wt3, bq, bk, bv, Qbf, Kb3, Vt3, blockIdx.x);
    grid_barrier(&bar[0], nb);
    phase_k2(smem, Qbf, Kb3, part, blockIdx.x * 2);
    phase_k2(smem, Qbf, Kb3, part, blockIdx.x * 2 + 1);
    grid_barrier(&bar[1], nb);
    phase_kab(smem, Qbf, Kb3, Vt3, mask, part, out, blockIdx.x);
}

extern "C" void kernel_launch(void* const* d_in, const int* in_sizes, int n_in,
                              void* d_out, int out_size, void* d_ws, size_t ws_size,
                              hipStream_t stream)
{
    const float* x    = (const float*)d_in[0];
    const float* mask = (const float*)d_in[1];
    const float* Wq   = (const float*)d_in[2];
    const float* bq   = (const float*)d_in[3];
    const float* Wk   = (const float*)d_in[4];
    const float* bk   = (const float*)d_in[5];
    const float* Wv   = (const float*)d_in[6];
    const float* bv   = (const float*)d_in[7];
    float* out = (float*)d_out;

    // ws layout (<4MB): Qbf 1MB | Kb3 1MB | Vt3 1MB | part 512KB | Wt3 384KB | bar
    char* ws = (char*)d_ws;
    __bf16* Qbf  = (__bf16*)(ws);
    __bf16* Kb3  = (__bf16*)(ws + (1u << 20));
    __bf16* Vt3  = (__bf16*)(ws + (2u << 20));
    float*  part = (float*)(ws + (3u << 20));
    __bf16* Wt3  = (__bf16*)(ws + (3u << 20) + (512u << 10));
    int*    bar  = (int*)(ws + (3u << 20) + (512u << 10) + (384u << 10));

    k0init<<<96, 256, 0, stream>>>(Wq, Wk, Wv, Wt3, bar);
    mega<<<512, 256, 0, stream>>>(x, mask, bq, bk, bv, Qbf, Kb3, Vt3, part, Wt3, bar, out);
}

// Round 16
// 59.648 us; speedup vs baseline: 3.6408x; 3.6408x over previous
//
#include <hip/hip_runtime.h>

#define NB 4
#define SS 2048
#define DMODEL 1024
#define DHEAD 64
// SCALE = sqrt(1024) = 32 exactly; folded into Wt3 for mode 0 (and bias at use).
// Softmax WITHOUT max subtraction: s ~ N(0,0.25), exp safe in f32.
// Softmax over the QUERY axis (reference quirk): r[k] = 1/sum_q exp(s[q,k]).
// R16 = R11 (best known, 54.9us) with kab reworked to 32-row q-tiles:
// grid 256 = 4b x 64 qp; each K/V fragment load feeds TWO q-subtiles
// (L2 traffic 268->134MB, line-requests/MFMA 20->12). R15's grid barriers
// reverted (agent-fence + spin cost ~90us/barrier — dead end).

typedef __bf16 bf16x8 __attribute__((ext_vector_type(8)));
typedef __bf16 bf16x4 __attribute__((ext_vector_type(4)));
typedef float f32x4 __attribute__((ext_vector_type(4)));

#define MFMA16(a, b, c) __builtin_amdgcn_mfma_f32_16x16x32_bf16((a), (b), (c), 0, 0, 0)

// Kb3 frag addr (elems): ((b*256 + t*2 + h) << 9) + ln*8 + i   (t=k>>4, h=d>>5)
// Vt3 frag addr (elems): ((b*256 + kc*4 + nt) << 9) + ln*8 + i (kc=k>>5, nt=d>>4)

// ---------------- Kernel 0: W -> Wt3 fragment-contiguous bf16 ----------------
__global__ __launch_bounds__(256) void k0_wt3(
    const float* __restrict__ Wq, const float* __restrict__ Wk,
    const float* __restrict__ Wv, __bf16* __restrict__ Wt3)
{
    int idx = blockIdx.x * 256 + threadIdx.x;  // 0..24575
    int kc = idx / 768;
    int rem = idx - kc * 768;
    int f = rem >> 6;
    int lane = rem & 63;
    int g = lane >> 4, l15 = lane & 15;
    int mode = f >> 2, nt = f & 3;
    const float* W = (mode == 0) ? Wq : (mode == 1 ? Wk : Wv);
    const float s = (mode == 0) ? 0.03125f : 1.0f;
    int n = nt * 16 + l15;
    int k = kc * 32 + g * 8;
    bf16x8 o;
    #pragma unroll
    for (int i = 0; i < 8; ++i)
        o[i] = (__bf16)(W[(size_t)(k + i) * DHEAD + n] * s);
    *(bf16x8*)(Wt3 + (size_t)idx * 8) = o;
}

// ---------------- Kernel 1: fused Q/K/V projection (R11-proven) -------------
#define XST 1032
__global__ __launch_bounds__(256) void k1_fused(
    const float* __restrict__ x, const __bf16* __restrict__ Wt3,
    const float* __restrict__ bq, const float* __restrict__ bk,
    const float* __restrict__ bv,
    __bf16* __restrict__ Qo, __bf16* __restrict__ Kb3, __bf16* __restrict__ Vt3)
{
    __shared__ char smem[43008];              // stage 33KB | red alias 36.9KB | outstage 6KB
    __bf16* stage = (__bf16*)smem;
    __bf16* outQ = (__bf16*)(smem + 36864);   // [16][64]
    __bf16* outK = outQ + 1024;               // 2 frags x 512 elems
    __bf16* outV = outK + 1024;               // 4 x 256 elems
    const int tid = threadIdx.x;
    const int wid = tid >> 6;
    const int lane = tid & 63;
    const int l15 = lane & 15;
    const int g = lane >> 4;
    const int row0 = blockIdx.x * 16;
    const int b  = row0 >> 11;
    const int s0 = row0 & 2047;
    const int soff = (s0 >> 3) & 2;

    {   // stage x[row0..+16][0..1024) f32 -> bf16, fully coalesced
        const float* xsrc = x + (size_t)row0 * DMODEL;
        #pragma unroll
        for (int it = 0; it < 16; ++it) {
            int idx = it * 256 + tid;
            int row = idx >> 8;
            int col = (idx & 255) * 4;
            f32x4 v = *(const f32x4*)(xsrc + (size_t)row * DMODEL + col);
            bf16x4 b4;
            #pragma unroll
            for (int i = 0; i < 4; ++i) b4[i] = (__bf16)v[i];
            *(bf16x4*)(stage + row * XST + col) = b4;
        }
    }
    __syncthreads();

    f32x4 acc[12];
    #pragma unroll
    for (int f = 0; f < 12; ++f) acc[f] = (f32x4){0.f, 0.f, 0.f, 0.f};

    #pragma unroll
    for (int c = 0; c < 8; ++c) {
        bf16x8 af = *(const bf16x8*)(stage + l15 * XST + wid * 256 + c * 32 + g * 8);
        const int kc = wid * 8 + c;
        #pragma unroll
        for (int f = 0; f < 12; ++f) {
            bf16x8 bfr = *(const bf16x8*)(Wt3 + (((size_t)kc * 12 + f) << 9) + lane * 8);
            acc[f] = MFMA16(af, bfr, acc[f]);
        }
    }
    __syncthreads();
    f32x4* red = (f32x4*)smem;                // [3][12][64] alias over stage
    if (wid != 0) {
        #pragma unroll
        for (int f = 0; f < 12; ++f) red[((wid - 1) * 12 + f) * 64 + lane] = acc[f];
    }
    __syncthreads();
    if (wid == 0) {
        #pragma unroll
        for (int f = 0; f < 12; ++f) {
            f32x4 a = acc[f] + red[(0 * 12 + f) * 64 + lane]
                    + red[(1 * 12 + f) * 64 + lane] + red[(2 * 12 + f) * 64 + lane];
            const int md = f >> 2, nt = f & 3;
            const int n = nt * 16 + l15;
            const float* bias = (md == 0) ? bq : (md == 1 ? bk : bv);
            const float bscale = (md == 0) ? 0.03125f : 1.0f;
            float bvl = bias[n] * bscale;
            #pragma unroll
            for (int r = 0; r < 4; ++r) {
                float o = a[r] + bvl;
                int g4r = g * 4 + r;
                if (md == 0) {
                    outQ[g4r * 64 + n] = (__bf16)o;
                } else if (md == 1) {
                    int ln = ((nt & 1) * 2 + (l15 >> 3)) * 16 + g4r;
                    outK[(nt >> 1) * 512 + ln * 8 + (l15 & 7)] = (__bf16)o;
                } else {
                    outV[nt * 256 + ((g4r >> 3) * 16 + l15) * 8 + (g4r & 7)] = (__bf16)o;
                }
            }
        }
    }
    __syncthreads();
    // cooperative coalesced stores
    if (tid < 128) {
        *(bf16x8*)(Qo + ((size_t)b * SS + s0) * DHEAD + tid * 8) = *(bf16x8*)(outQ + tid * 8);
        int nt = tid >> 5, e = (tid & 31) * 8;
        *(bf16x8*)(Vt3 + (((size_t)(b * 256 + (s0 >> 5) * 4 + nt)) << 9) + soff * 128 + e)
            = *(bf16x8*)(outV + nt * 256 + e);
    } else {
        int t2 = tid - 128;
        *(bf16x8*)(Kb3 + (((size_t)b * 256 + (s0 >> 4) * 2) << 9) + t2 * 8) = *(bf16x8*)(outK + t2 * 8);
    }
}

// ---------------- Kernel 2: column exp-sum partials (R11-proven) ------------
#define QST 72
__global__ __launch_bounds__(256) void k2_cs(
    const __bf16* __restrict__ Qb, const __bf16* __restrict__ Kb3,
    float* __restrict__ partial)
{
    __shared__ __bf16 qt[128 * QST];          // 18.4 KB
    const int tid = threadIdx.x;
    const int wid = tid >> 6;
    const int lane = tid & 63;
    const int l15 = lane & 15;
    const int g = lane >> 4;
    const int bx = blockIdx.x;
    const int b  = bx >> 8;
    const int rem = bx & 255;
    const int kg = rem >> 4;
    const int qs = rem & 15;
    const int k0 = kg * 128 + wid * 32;

    {   // stage Q rows [qs*128,+128): 16 KB contiguous
        const __bf16* qsrc = Qb + ((size_t)(b * SS + qs * 128)) * DHEAD;
        #pragma unroll
        for (int it = 0; it < 4; ++it) {
            int idx = it * 256 + tid;
            int row = idx >> 3;
            int col = (idx & 7) * 8;
            *(bf16x8*)(qt + row * QST + col) = *(const bf16x8*)(qsrc + (size_t)idx * 8);
        }
    }

    const __bf16* kfr = Kb3 + (((size_t)b * 256 + (k0 >> 4) * 2) << 9) + lane * 8;
    bf16x8 ka00 = *(const bf16x8*)(kfr);
    bf16x8 ka01 = *(const bf16x8*)(kfr + 512);
    bf16x8 ka10 = *(const bf16x8*)(kfr + 1024);
    bf16x8 ka11 = *(const bf16x8*)(kfr + 1536);
    __syncthreads();

    f32x4 cs0 = (f32x4){0.f, 0.f, 0.f, 0.f};
    f32x4 cs1 = (f32x4){0.f, 0.f, 0.f, 0.f};

    #pragma unroll 2
    for (int j = 0; j < 8; ++j) {
        const __bf16* qr = qt + (j * 16 + l15) * QST + g * 8;
        bf16x8 qb0 = *(const bf16x8*)(qr);
        bf16x8 qb1 = *(const bf16x8*)(qr + 32);
        f32x4 s0 = (f32x4){0.f, 0.f, 0.f, 0.f};
        s0 = MFMA16(ka00, qb0, s0);
        s0 = MFMA16(ka01, qb1, s0);
        f32x4 s1 = (f32x4){0.f, 0.f, 0.f, 0.f};
        s1 = MFMA16(ka10, qb0, s1);
        s1 = MFMA16(ka11, qb1, s1);
        #pragma unroll
        for (int r = 0; r < 4; ++r) {
            cs0[r] += __expf(s0[r]);
            cs1[r] += __expf(s1[r]);
        }
    }
    #pragma unroll
    for (int off = 1; off < 16; off <<= 1) {
        #pragma unroll
        for (int r = 0; r < 4; ++r) {
            cs0[r] += __shfl_xor(cs0[r], off);
            cs1[r] += __shfl_xor(cs1[r], off);
        }
    }
    if (l15 == 0) {
        float* pp = partial + (size_t)qs * (NB * SS) + b * SS + k0 + 4 * g;
        *(f32x4*)(pp)      = cs0;
        *(f32x4*)(pp + 16) = cs1;
    }
}

// ---------------- Kernel AB: out = (exp(S).*r + mask) @ V  (32-q tiles) -----
// grid 256 = 4b x 64 qp(32 rows); block 512 = 8 waves; wave wid owns k-range
// [wid*256,+256) = 8 steps of 32. Per step: 4 K + 4 V coalesced frag loads
// feed TWO q-subtiles (A: q0.., B: q0+16..): 8 QK MFMA + exp*r + 2x shuffle
// transpose (R11-proven) + direct mask A-frag loads (R14-proven) + 8 PV MFMA.
// Barrier-free loop; two-round LDS reduce; coalesced f32x4 stores.
__global__ __launch_bounds__(512) void kab(
    const __bf16* __restrict__ Qb, const __bf16* __restrict__ Kb3,
    const __bf16* __restrict__ Vt3, const float* __restrict__ mask,
    const float* __restrict__ part, float* __restrict__ out)
{
    __shared__ char smem[40960];              // rl/outO 8KB | red 32KB @8192
    float* rl = (float*)smem;
    f32x4* red = (f32x4*)(smem + 8192);       // [8][4][64]
    const int tid = threadIdx.x;
    const int wid = tid >> 6;
    const int lane = tid & 63;
    const int l15 = lane & 15;
    const int g = lane >> 4;
    const int b  = blockIdx.x >> 6;
    const int q0 = (blockIdx.x & 63) * 32;

    {   // r prologue: 4 k per thread (512 thr x 4 = 2048)
        const int k = tid * 4;
        f32x4 s = (f32x4){0.f, 0.f, 0.f, 0.f};
        #pragma unroll
        for (int qs = 0; qs < 16; ++qs)
            s += *(const f32x4*)(part + (size_t)qs * (NB * SS) + b * SS + k);
        f32x4 rr;
        #pragma unroll
        for (int r = 0; r < 4; ++r) rr[r] = 1.0f / s[r];
        *(f32x4*)(rl + k) = rr;
    }

    // hoisted Q B-frags for both subtiles
    const __bf16* qpA = Qb + ((size_t)(b * SS + q0 + l15)) * DHEAD + g * 8;
    bf16x8 qa0 = *(const bf16x8*)(qpA);
    bf16x8 qa1 = *(const bf16x8*)(qpA + 32);
    const __bf16* qpB = qpA + 16 * DHEAD;
    bf16x8 qc0 = *(const bf16x8*)(qpB);
    bf16x8 qc1 = *(const bf16x8*)(qpB + 32);
    __syncthreads();                          // rl ready

    f32x4 accA[4], accB[4];
    #pragma unroll
    for (int nt = 0; nt < 4; ++nt) {
        accA[nt] = (f32x4){0.f, 0.f, 0.f, 0.f};
        accB[nt] = (f32x4){0.f, 0.f, 0.f, 0.f};
    }
    const float* mrowA = mask + ((size_t)(b * SS + q0 + l15)) * SS + g * 8;
    const float* mrowB = mrowA + (size_t)16 * SS;

    #pragma unroll 2
    for (int st = 0; st < 8; ++st) {
        const int kbase = wid * 256 + st * 32;
        const __bf16* kfr = Kb3 + (((size_t)b * 256 + (kbase >> 4) * 2) << 9) + lane * 8;
        bf16x8 ka00 = *(const bf16x8*)(kfr);
        bf16x8 ka01 = *(const bf16x8*)(kfr + 512);
        bf16x8 ka10 = *(const bf16x8*)(kfr + 1024);
        bf16x8 ka11 = *(const bf16x8*)(kfr + 1536);
        const __bf16* vfr = Vt3 + (((size_t)b * 256 + (kbase >> 5) * 4) << 9) + lane * 8;
        bf16x8 vb0 = *(const bf16x8*)(vfr);
        bf16x8 vb1 = *(const bf16x8*)(vfr + 512);
        bf16x8 vb2 = *(const bf16x8*)(vfr + 1024);
        bf16x8 vb3 = *(const bf16x8*)(vfr + 1536);
        f32x4 mkA0 = *(const f32x4*)(mrowA + kbase);
        f32x4 mkA1 = *(const f32x4*)(mrowA + kbase + 4);
        f32x4 mkB0 = *(const f32x4*)(mrowB + kbase);
        f32x4 mkB1 = *(const f32x4*)(mrowB + kbase + 4);

        // QK for both subtiles (K frags shared)
        f32x4 sA0 = (f32x4){0.f, 0.f, 0.f, 0.f};
        sA0 = MFMA16(ka00, qa0, sA0);
        sA0 = MFMA16(ka01, qa1, sA0);
        f32x4 sA1 = (f32x4){0.f, 0.f, 0.f, 0.f};
        sA1 = MFMA16(ka10, qa0, sA1);
        sA1 = MFMA16(ka11, qa1, sA1);
        f32x4 sB0 = (f32x4){0.f, 0.f, 0.f, 0.f};
        sB0 = MFMA16(ka00, qc0, sB0);
        sB0 = MFMA16(ka01, qc1, sB0);
        f32x4 sB1 = (f32x4){0.f, 0.f, 0.f, 0.f};
        sB1 = MFMA16(ka10, qc0, sB1);
        sB1 = MFMA16(ka11, qc1, sB1);

        f32x4 rv0 = *(const f32x4*)(rl + kbase + 4 * g);
        f32x4 rv1 = *(const f32x4*)(rl + kbase + 16 + 4 * g);
        f32x4 eA0, eA1, eB0, eB1;
        #pragma unroll
        for (int r = 0; r < 4; ++r) {
            eA0[r] = __expf(sA0[r]) * rv0[r];
            eA1[r] = __expf(sA1[r]) * rv1[r];
            eB0[r] = __expf(sB0[r]) * rv0[r];
            eB1[r] = __expf(sB1[r]) * rv1[r];
        }
        // shuffle transpose (R11-proven) + direct mask add (R14-proven)
        bf16x8 afA, afB;
        #pragma unroll
        for (int i = 0; i < 8; ++i) {
            int src = l15 + 16 * ((2 * g + (i >> 2)) & 3);
            float a0 = __shfl(eA0[i & 3], src);
            float a1 = __shfl(eA1[i & 3], src);
            afA[i] = (__bf16)((g < 2 ? a0 : a1) + (i < 4 ? mkA0[i & 3] : mkA1[i & 3]));
            float b0 = __shfl(eB0[i & 3], src);
            float b1 = __shfl(eB1[i & 3], src);
            afB[i] = (__bf16)((g < 2 ? b0 : b1) + (i < 4 ? mkB0[i & 3] : mkB1[i & 3]));
        }
        accA[0] = MFMA16(afA, vb0, accA[0]);
        accA[1] = MFMA16(afA, vb1, accA[1]);
        accA[2] = MFMA16(afA, vb2, accA[2]);
        accA[3] = MFMA16(afA, vb3, accA[3]);
        accB[0] = MFMA16(afB, vb0, accB[0]);
        accB[1] = MFMA16(afB, vb1, accB[1]);
        accB[2] = MFMA16(afB, vb2, accB[2]);
        accB[3] = MFMA16(afB, vb3, accB[3]);
    }
    __syncthreads();
    float* outO = (float*)smem;               // [32][64] f32 = 8KB alias (rl dead)
    // round A
    #pragma unroll
    for (int nt = 0; nt < 4; ++nt) red[(wid * 4 + nt) * 64 + lane] = accA[nt];
    __syncthreads();
    if (wid < 4) {
        const int nt = wid;
        f32x4 a = red[nt * 64 + lane];
        #pragma unroll
        for (int w = 1; w < 8; ++w) a += red[(w * 4 + nt) * 64 + lane];
        #pragma unroll
        for (int r = 0; r < 4; ++r)
            outO[(g * 4 + r) * 64 + nt * 16 + l15] = a[r];
    }
    __syncthreads();
    // round B
    #pragma unroll
    for (int nt = 0; nt < 4; ++nt) red[(wid * 4 + nt) * 64 + lane] = accB[nt];
    __syncthreads();
    if (wid < 4) {
        const int nt = wid;
        f32x4 a = red[nt * 64 + lane];
        #pragma unroll
        for (int w = 1; w < 8; ++w) a += red[(w * 4 + nt) * 64 + lane];
        #pragma unroll
        for (int r = 0; r < 4; ++r)
            outO[(16 + g * 4 + r) * 64 + nt * 16 + l15] = a[r];
    }
    __syncthreads();
    {   // coalesced stores: 512 thr x f32x4 = 32 rows x 64 cols
        int row = tid >> 4, col = (tid & 15) * 4;
        *(f32x4*)(out + ((size_t)(b * SS + q0 + row)) * DHEAD + col)
            = *(const f32x4*)(outO + row * 64 + col);
    }
}

extern "C" void kernel_launch(void* const* d_in, const int* in_sizes, int n_in,
                              void* d_out, int out_size, void* d_ws, size_t ws_size,
                              hipStream_t stream)
{
    const float* x    = (const float*)d_in[0];
    const float* mask = (const float*)d_in[1];
    const float* Wq   = (const float*)d_in[2];
    const float* bq   = (const float*)d_in[3];
    const float* Wk   = (const float*)d_in[4];
    const float* bk   = (const float*)d_in[5];
    const float* Wv   = (const float*)d_in[6];
    const float* bv   = (const float*)d_in[7];
    float* out = (float*)d_out;

    // ws layout (<4MB): Qbf 1MB | Kb3 1MB | Vt3 1MB | part 512KB | Wt3 384KB
    char* ws = (char*)d_ws;
    __bf16* Qbf  = (__bf16*)(ws);
    __bf16* Kb3  = (__bf16*)(ws + (1u << 20));
    __bf16* Vt3  = (__bf16*)(ws + (2u << 20));
    float*  part = (float*)(ws + (3u << 20));
    __bf16* Wt3  = (__bf16*)(ws + (3u << 20) + (512u << 10));

    k0_wt3<<<96, 256, 0, stream>>>(Wq, Wk, Wv, Wt3);
    k1_fused<<<512, 256, 0, stream>>>(x, Wt3, bq, bk, bv, Qbf, Kb3, Vt3);
    k2_cs<<<1024, 256, 0, stream>>>(Qbf, Kb3, part);
    kab<<<256, 512, 0, stream>>>(Qbf, Kb3, Vt3, mask, part, out);
}